// Round 5
// baseline (773.454 us; speedup 1.0000x reference)
//
#include <hip/hip_runtime.h>
#include <hip/hip_bf16.h>

// GraphConv x2 — bisect round: pre-transform built ONLY from round-2-proven
// pieces, all f32, no new gather geometry.
//   CSR by dst (hist->scan->fill), built once (proven).
//   Layer l:  gemm:   xr = x @ Wrel^T ;  io = x @ Wroot^T + b     (io==d_out)
//             gather: io[i] = [relu]( sum_j w_j * xr[src_j] + io[i] )  in place
//   d_out carries h between layers (f32); gemm2 updates d_out row-locally.
//   Workspace = 39,204,112 B (proven round-2 footprint).
// N=100000, E=1600000, D=64

#define D 64
#define SCAN_CHUNK 1024

// ---------------- CSR build (verbatim round 2, proven) ----------------
__global__ __launch_bounds__(256) void hist_kernel(
    const int* __restrict__ ei, int* __restrict__ deg, int E_)
{
    int e = blockIdx.x * 256 + threadIdx.x;
    if (e >= E_) return;
    atomicAdd(&deg[ei[E_ + e]], 1);
}

__global__ __launch_bounds__(256) void scan1_kernel(
    const int* __restrict__ deg, int* __restrict__ loc, int* __restrict__ partial, int n)
{
    __shared__ int wsum[4];
    int t = threadIdx.x;
    int base = blockIdx.x * SCAN_CHUNK + t * 4;
    int v0 = (base + 0 < n) ? deg[base + 0] : 0;
    int v1 = (base + 1 < n) ? deg[base + 1] : 0;
    int v2 = (base + 2 < n) ? deg[base + 2] : 0;
    int v3 = (base + 3 < n) ? deg[base + 3] : 0;
    int s = v0 + v1 + v2 + v3;
    int lane = t & 63, wave = t >> 6;
    int inc = s;
    for (int off = 1; off < 64; off <<= 1) {
        int u = __shfl_up(inc, off);
        if (lane >= off) inc += u;
    }
    if (lane == 63) wsum[wave] = inc;
    __syncthreads();
    int woff = 0;
    for (int w = 0; w < wave; ++w) woff += wsum[w];
    int ex = woff + inc - s;
    if (base + 0 < n) loc[base + 0] = ex;
    if (base + 1 < n) loc[base + 1] = ex + v0;
    if (base + 2 < n) loc[base + 2] = ex + v0 + v1;
    if (base + 3 < n) loc[base + 3] = ex + v0 + v1 + v2;
    if (t == 255) partial[blockIdx.x] = woff + inc;
}

__global__ __launch_bounds__(1024) void scan2_kernel(int* __restrict__ partial, int nchunk)
{
    __shared__ int sd[1024];
    int t = threadIdx.x;
    if (t < nchunk) sd[t] = partial[t];
    __syncthreads();
    if (t == 0) {
        int run = 0;
        for (int i = 0; i < nchunk; ++i) { int v = sd[i]; sd[i] = run; run += v; }
    }
    __syncthreads();
    if (t < nchunk) partial[t] = sd[t];
}

__global__ __launch_bounds__(256) void scan3_kernel(
    int* __restrict__ rowptr, const int* __restrict__ partial,
    int* __restrict__ cursor, int n, int Etot)
{
    int i = blockIdx.x * 256 + threadIdx.x;
    if (i == 0) rowptr[n] = Etot;
    if (i >= n) return;
    int v = rowptr[i] + partial[i >> 10];
    rowptr[i] = v;
    cursor[i] = v;
}

__global__ __launch_bounds__(256) void fill_kernel(
    const int* __restrict__ ei, const float* __restrict__ ew,
    int* __restrict__ cursor, float2* __restrict__ pairs, int E_)
{
    int e = blockIdx.x * 256 + threadIdx.x;
    if (e >= E_) return;
    int src = ei[e];
    int dst = ei[E_ + e];
    int p = atomicAdd(&cursor[dst], 1);
    pairs[p] = make_float2(__int_as_float(src), ew[e]);
}

// ---------------- pre-transform GEMM (round-2 fused_layer pattern, minus gather) ----------------
// xr[i] = xin[i] @ Wrel^T ;  io[i] = xin[i] @ Wroot^T + b.
// xin MAY ALIAS io (layer 2: both d_out) — row read happens before row write
// in the same wave; no __restrict__ on xin/io.
#define GW 8
__global__ __launch_bounds__(512) void gemm_kernel(
    const float* xin,
    const float* __restrict__ Wrel, const float* __restrict__ brel,
    const float* __restrict__ Wroot,
    float* __restrict__ xr, float* io, int Nn)
{
    __shared__ float WrelT[D * D];   // WrelT[k*64+d] = Wrel[d*64+k]
    __shared__ float WrootT[D * D];
    __shared__ float bias[D];
    __shared__ float rowX[GW][D];

    int tid = threadIdx.x;
    for (int i = tid; i < D * D; i += 512) {
        int d = i >> 6, k = i & 63;
        WrelT [k * D + d] = Wrel [i];
        WrootT[k * D + d] = Wroot[i];
    }
    if (tid < D) bias[tid] = brel[tid];
    __syncthreads();

    int wave = tid >> 6, lane = tid & 63;
    int i = blockIdx.x * GW + wave;
    if (i >= Nn) return;                       // wave-uniform, after barrier

    rowX[wave][lane] = xin[(size_t)i * D + lane];
    // same-wave LDS write->read (in-order per wave)

    const float4* rX4 = reinterpret_cast<const float4*>(rowX[wave]);
    float aR = 0.f;
    float aC = bias[lane];
#pragma unroll
    for (int k4 = 0; k4 < 16; ++k4) {
        float4 xv = rX4[k4];                   // broadcast b128
        int k = k4 * 4;
        aR += xv.x * WrelT [(k + 0) * D + lane];
        aR += xv.y * WrelT [(k + 1) * D + lane];
        aR += xv.z * WrelT [(k + 2) * D + lane];
        aR += xv.w * WrelT [(k + 3) * D + lane];
        aC += xv.x * WrootT[(k + 0) * D + lane];
        aC += xv.y * WrootT[(k + 1) * D + lane];
        aC += xv.z * WrootT[(k + 2) * D + lane];
        aC += xv.w * WrootT[(k + 3) * D + lane];
    }
    size_t o = (size_t)i * D + lane;
    xr[o] = aR;
    io[o] = aC;
}

// ---------------- gather (round-2 loop verbatim, in-place epilogue) ----------------
#define AW 8
template <bool RELU>
__global__ __launch_bounds__(512) void gather_kernel(
    const float* __restrict__ xr, const float2* __restrict__ pairs,
    const int* __restrict__ rowptr, float* __restrict__ io, int Nn)
{
    int tid  = threadIdx.x;
    int wave = tid >> 6, lane = tid & 63;
    int i = blockIdx.x * AW + wave;
    if (i >= Nn) return;                       // wave-uniform

    int beg = rowptr[i], end = rowptr[i + 1];
    float acc = 0.f;
    for (int b = beg; b < end; b += 64) {
        int cnt = min(64, end - b);
        float2 pr = (lane < cnt) ? pairs[b + lane] : make_float2(0.f, 0.f);
        int ps = __float_as_int(pr.x);
        int j = 0;
        for (; j + 4 <= cnt; j += 4) {         // 4 independent gathers in flight
            int   s0 = __shfl(ps, j),     s1 = __shfl(ps, j + 1);
            int   s2 = __shfl(ps, j + 2), s3 = __shfl(ps, j + 3);
            float w0 = __shfl(pr.y, j),     w1 = __shfl(pr.y, j + 1);
            float w2 = __shfl(pr.y, j + 2), w3 = __shfl(pr.y, j + 3);
            float v0 = xr[(size_t)s0 * D + lane];
            float v1 = xr[(size_t)s1 * D + lane];
            float v2 = xr[(size_t)s2 * D + lane];
            float v3 = xr[(size_t)s3 * D + lane];
            acc += v0 * w0; acc += v1 * w1; acc += v2 * w2; acc += v3 * w3;
        }
        for (; j < cnt; ++j) {
            int s = __shfl(ps, j);
            float w = __shfl(pr.y, j);
            acc += xr[(size_t)s * D + lane] * w;
        }
    }
    size_t o = (size_t)i * D + lane;
    float v = acc + io[o];
    io[o] = RELU ? fmaxf(v, 0.f) : v;
}

extern "C" void kernel_launch(void* const* d_in, const int* in_sizes, int n_in,
                              void* d_out, int out_size, void* d_ws, size_t ws_size,
                              hipStream_t stream)
{
    const float* x      = (const float*)d_in[0];
    const int*   ei     = (const int*)  d_in[1];
    const float* ew     = (const float*)d_in[2];
    const float* Wrel1  = (const float*)d_in[3];
    const float* brel1  = (const float*)d_in[4];
    const float* Wroot1 = (const float*)d_in[5];
    const float* Wrel2  = (const float*)d_in[6];
    const float* brel2  = (const float*)d_in[7];
    const float* Wroot2 = (const float*)d_in[8];
    float* out = (float*)d_out;

    const int E_ = in_sizes[2];          // 1600000
    const int Nn = in_sizes[0] / D;      // 100000

    // workspace layout — 39,204,112 B total (proven round-2 footprint)
    char* w = (char*)d_ws;
    size_t off = 0;
    float* xr     = (float*)(w + off); off += (size_t)Nn * D * sizeof(float); // 25.6 MB
    int*   rowptr = (int*)  (w + off); off += (size_t)(Nn + 1) * sizeof(int);
    int*   cursor = (int*)  (w + off); off += (size_t)Nn * sizeof(int);
    int*   partial= (int*)  (w + off); off += 1024 * sizeof(int);
    off = (off + 15) & ~(size_t)15;
    float2* pairs = (float2*)(w + off);                                       // 12.8 MB

    const int nchunk  = (Nn + SCAN_CHUNK - 1) / SCAN_CHUNK;
    const int eBlocks = (E_ + 255) / 256;
    const int gemmBlocks   = (Nn + GW - 1) / GW;
    const int gatherBlocks = (Nn + AW - 1) / AW;

    // ---- CSR build (reused by both layers) ----
    hipMemsetAsync(cursor, 0, (size_t)Nn * sizeof(int), stream);
    hist_kernel<<<eBlocks, 256, 0, stream>>>(ei, cursor, E_);
    scan1_kernel<<<nchunk, 256, 0, stream>>>(cursor, rowptr, partial, Nn);
    scan2_kernel<<<1, 1024, 0, stream>>>(partial, nchunk);
    scan3_kernel<<<(Nn + 255) / 256, 256, 0, stream>>>(rowptr, partial, cursor, Nn, E_);
    fill_kernel<<<eBlocks, 256, 0, stream>>>(ei, ew, cursor, pairs, E_);

    // ---- layer 1: out = x@Wroot1^T+b1;  out = relu(gather(xr1) + out)  (h lives in d_out) ----
    gemm_kernel<<<gemmBlocks, 512, 0, stream>>>(x, Wrel1, brel1, Wroot1, xr, out, Nn);
    gather_kernel<true><<<gatherBlocks, 512, 0, stream>>>(xr, pairs, rowptr, out, Nn);

    // ---- layer 2: xr2 = h@Wrel2^T; out = h@Wroot2^T+b2 (in place);  out += gather(xr2) ----
    gemm_kernel<<<gemmBlocks, 512, 0, stream>>>(out, Wrel2, brel2, Wroot2, xr, out, Nn);
    gather_kernel<false><<<gatherBlocks, 512, 0, stream>>>(xr, pairs, rowptr, out, Nn);
}

// Round 6
// 410.364 us; speedup vs baseline: 1.8848x; 1.8848x over previous
//
#include <hip/hip_runtime.h>
#include <hip/hip_bf16.h>

// GraphConv x2 — round 6: round-5 passing base + GR=4 padded-LDS gemm.
//   CSR by dst (proven). Per layer:
//     gemm:   xr = x @ Wrel^T ;  io = x @ Wroot^T + b     (io==d_out, f32)
//     gather: io[i] = [relu]( sum_j w_j * xr[src_j] + io[i] )  in place (round-5 verbatim)
//   gemm fix: [64][65]-padded weight LDS (staging writes AND reads conflict-free),
//   4 rows/wave to amortize weight reads. All f32.
// N=100000, E=1600000, D=64

#define D 64
#define SCAN_CHUNK 1024

// ---------------- CSR build (round-5 verbatim, proven) ----------------
__global__ __launch_bounds__(256) void hist_kernel(
    const int* __restrict__ ei, int* __restrict__ deg, int E_)
{
    int e = blockIdx.x * 256 + threadIdx.x;
    if (e >= E_) return;
    atomicAdd(&deg[ei[E_ + e]], 1);
}

__global__ __launch_bounds__(256) void scan1_kernel(
    const int* __restrict__ deg, int* __restrict__ loc, int* __restrict__ partial, int n)
{
    __shared__ int wsum[4];
    int t = threadIdx.x;
    int base = blockIdx.x * SCAN_CHUNK + t * 4;
    int v0 = (base + 0 < n) ? deg[base + 0] : 0;
    int v1 = (base + 1 < n) ? deg[base + 1] : 0;
    int v2 = (base + 2 < n) ? deg[base + 2] : 0;
    int v3 = (base + 3 < n) ? deg[base + 3] : 0;
    int s = v0 + v1 + v2 + v3;
    int lane = t & 63, wave = t >> 6;
    int inc = s;
    for (int off = 1; off < 64; off <<= 1) {
        int u = __shfl_up(inc, off);
        if (lane >= off) inc += u;
    }
    if (lane == 63) wsum[wave] = inc;
    __syncthreads();
    int woff = 0;
    for (int w = 0; w < wave; ++w) woff += wsum[w];
    int ex = woff + inc - s;
    if (base + 0 < n) loc[base + 0] = ex;
    if (base + 1 < n) loc[base + 1] = ex + v0;
    if (base + 2 < n) loc[base + 2] = ex + v0 + v1;
    if (base + 3 < n) loc[base + 3] = ex + v0 + v1 + v2;
    if (t == 255) partial[blockIdx.x] = woff + inc;
}

__global__ __launch_bounds__(1024) void scan2_kernel(int* __restrict__ partial, int nchunk)
{
    __shared__ int sd[1024];
    int t = threadIdx.x;
    if (t < nchunk) sd[t] = partial[t];
    __syncthreads();
    if (t == 0) {
        int run = 0;
        for (int i = 0; i < nchunk; ++i) { int v = sd[i]; sd[i] = run; run += v; }
    }
    __syncthreads();
    if (t < nchunk) partial[t] = sd[t];
}

__global__ __launch_bounds__(256) void scan3_kernel(
    int* __restrict__ rowptr, const int* __restrict__ partial,
    int* __restrict__ cursor, int n, int Etot)
{
    int i = blockIdx.x * 256 + threadIdx.x;
    if (i == 0) rowptr[n] = Etot;
    if (i >= n) return;
    int v = rowptr[i] + partial[i >> 10];
    rowptr[i] = v;
    cursor[i] = v;
}

__global__ __launch_bounds__(256) void fill_kernel(
    const int* __restrict__ ei, const float* __restrict__ ew,
    int* __restrict__ cursor, float2* __restrict__ pairs, int E_)
{
    int e = blockIdx.x * 256 + threadIdx.x;
    if (e >= E_) return;
    int src = ei[e];
    int dst = ei[E_ + e];
    int p = atomicAdd(&cursor[dst], 1);
    pairs[p] = make_float2(__int_as_float(src), ew[e]);
}

// ---------------- pre-transform GEMM, GR=4 rows/wave, padded LDS ----------------
// xr[i] = xin[i] @ Wrel^T ;  io[i] = xin[i] @ Wroot^T + b.
// xin MAY ALIAS io (layer 2) — each row is read before that same row is
// written, by the same wave; rows are partitioned across waves.
#define GW 8   // waves/block (512 threads)
#define GR 4   // rows/wave
__global__ __launch_bounds__(512) void gemm_kernel(
    const float* xin,
    const float* __restrict__ Wrel, const float* __restrict__ brel,
    const float* __restrict__ Wroot,
    float* __restrict__ xr, float* io, int Nn)
{
    __shared__ float WrelT[D][D + 1];   // WrelT[k][d] = Wrel[d*64+k]; pad kills conflicts
    __shared__ float WrootT[D][D + 1];
    __shared__ float bias[D];
    __shared__ float rowX[GW][GR][D];   // write bank=lane%32 (2-way, free); reads broadcast

    int tid = threadIdx.x;
    for (int i = tid; i < D * D; i += 512) {
        int d = i >> 6, k = i & 63;     // within a wave: d const, k=0..63 -> bank (k+d)%32
        WrelT [k][d] = Wrel [i];
        WrootT[k][d] = Wroot[i];
    }
    if (tid < D) bias[tid] = brel[tid];
    __syncthreads();

    int wave = tid >> 6, lane = tid & 63;

    int base = (blockIdx.x * GW + wave) * GR;
    if (base >= Nn) return;             // wave-uniform, after barrier
    int nr = min(GR, Nn - base);

    for (int r = 0; r < nr; ++r)
        rowX[wave][r][lane] = xin[(size_t)(base + r) * D + lane];
    // same-wave LDS write->read: DS ops issue in order per wave (round-2/5-proven)

    float aR[GR] = {0.f, 0.f, 0.f, 0.f};
    float aC[GR] = {0.f, 0.f, 0.f, 0.f};
#pragma unroll
    for (int k4 = 0; k4 < 16; ++k4) {
        float4 xv[GR];
#pragma unroll
        for (int r = 0; r < GR; ++r)
            xv[r] = *reinterpret_cast<const float4*>(&rowX[wave][r][k4 * 4]); // broadcast b128
#pragma unroll
        for (int kk = 0; kk < 4; ++kk) {
            float wr = WrelT [k4 * 4 + kk][lane];   // bank (k+lane)%32: conflict-free
            float wc = WrootT[k4 * 4 + kk][lane];
#pragma unroll
            for (int r = 0; r < GR; ++r) {
                float xk = (kk == 0) ? xv[r].x : (kk == 1) ? xv[r].y
                         : (kk == 2) ? xv[r].z : xv[r].w;   // static after unroll
                aR[r] = fmaf(xk, wr, aR[r]);
                aC[r] = fmaf(xk, wc, aC[r]);
            }
        }
    }
    for (int r = 0; r < nr; ++r) {
        size_t o = (size_t)(base + r) * D + lane;
        xr[o] = aR[r];
        io[o] = aC[r] + bias[lane];
    }
}

// ---------------- gather (round-5 verbatim, proven) ----------------
#define AW 8
template <bool RELU>
__global__ __launch_bounds__(512) void gather_kernel(
    const float* __restrict__ xr, const float2* __restrict__ pairs,
    const int* __restrict__ rowptr, float* __restrict__ io, int Nn)
{
    int tid  = threadIdx.x;
    int wave = tid >> 6, lane = tid & 63;
    int i = blockIdx.x * AW + wave;
    if (i >= Nn) return;                       // wave-uniform

    int beg = rowptr[i], end = rowptr[i + 1];
    float acc = 0.f;
    for (int b = beg; b < end; b += 64) {
        int cnt = min(64, end - b);
        float2 pr = (lane < cnt) ? pairs[b + lane] : make_float2(0.f, 0.f);
        int ps = __float_as_int(pr.x);
        int j = 0;
        for (; j + 4 <= cnt; j += 4) {         // 4 independent gathers in flight
            int   s0 = __shfl(ps, j),     s1 = __shfl(ps, j + 1);
            int   s2 = __shfl(ps, j + 2), s3 = __shfl(ps, j + 3);
            float w0 = __shfl(pr.y, j),     w1 = __shfl(pr.y, j + 1);
            float w2 = __shfl(pr.y, j + 2), w3 = __shfl(pr.y, j + 3);
            float v0 = xr[(size_t)s0 * D + lane];
            float v1 = xr[(size_t)s1 * D + lane];
            float v2 = xr[(size_t)s2 * D + lane];
            float v3 = xr[(size_t)s3 * D + lane];
            acc += v0 * w0; acc += v1 * w1; acc += v2 * w2; acc += v3 * w3;
        }
        for (; j < cnt; ++j) {
            int s = __shfl(ps, j);
            float w = __shfl(pr.y, j);
            acc += xr[(size_t)s * D + lane] * w;
        }
    }
    size_t o = (size_t)i * D + lane;
    float v = acc + io[o];
    io[o] = RELU ? fmaxf(v, 0.f) : v;
}

extern "C" void kernel_launch(void* const* d_in, const int* in_sizes, int n_in,
                              void* d_out, int out_size, void* d_ws, size_t ws_size,
                              hipStream_t stream)
{
    const float* x      = (const float*)d_in[0];
    const int*   ei     = (const int*)  d_in[1];
    const float* ew     = (const float*)d_in[2];
    const float* Wrel1  = (const float*)d_in[3];
    const float* brel1  = (const float*)d_in[4];
    const float* Wroot1 = (const float*)d_in[5];
    const float* Wrel2  = (const float*)d_in[6];
    const float* brel2  = (const float*)d_in[7];
    const float* Wroot2 = (const float*)d_in[8];
    float* out = (float*)d_out;

    const int E_ = in_sizes[2];          // 1600000
    const int Nn = in_sizes[0] / D;      // 100000

    // workspace layout — 39,204,112 B total (proven footprint)
    char* w = (char*)d_ws;
    size_t off = 0;
    float* xr     = (float*)(w + off); off += (size_t)Nn * D * sizeof(float); // 25.6 MB
    int*   rowptr = (int*)  (w + off); off += (size_t)(Nn + 1) * sizeof(int);
    int*   cursor = (int*)  (w + off); off += (size_t)Nn * sizeof(int);
    int*   partial= (int*)  (w + off); off += 1024 * sizeof(int);
    off = (off + 15) & ~(size_t)15;
    float2* pairs = (float2*)(w + off);                                       // 12.8 MB

    const int nchunk  = (Nn + SCAN_CHUNK - 1) / SCAN_CHUNK;
    const int eBlocks = (E_ + 255) / 256;
    const int gemmBlocks   = (Nn + GW * GR - 1) / (GW * GR);
    const int gatherBlocks = (Nn + AW - 1) / AW;

    // ---- CSR build (reused by both layers) ----
    hipMemsetAsync(cursor, 0, (size_t)Nn * sizeof(int), stream);
    hist_kernel<<<eBlocks, 256, 0, stream>>>(ei, cursor, E_);
    scan1_kernel<<<nchunk, 256, 0, stream>>>(cursor, rowptr, partial, Nn);
    scan2_kernel<<<1, 1024, 0, stream>>>(partial, nchunk);
    scan3_kernel<<<(Nn + 255) / 256, 256, 0, stream>>>(rowptr, partial, cursor, Nn, E_);
    fill_kernel<<<eBlocks, 256, 0, stream>>>(ei, ew, cursor, pairs, E_);

    // ---- layer 1: out = x@Wroot1^T+b1;  out = relu(gather(xr1) + out) ----
    gemm_kernel<<<gemmBlocks, 512, 0, stream>>>(x, Wrel1, brel1, Wroot1, xr, out, Nn);
    gather_kernel<true><<<gatherBlocks, 512, 0, stream>>>(xr, pairs, rowptr, out, Nn);

    // ---- layer 2: xr2 = h@Wrel2^T; out = h@Wroot2^T+b2 (in place);  out += gather(xr2) ----
    gemm_kernel<<<gemmBlocks, 512, 0, stream>>>(out, Wrel2, brel2, Wroot2, xr, out, Nn);
    gather_kernel<false><<<gatherBlocks, 512, 0, stream>>>(xr, pairs, rowptr, out, Nn);
}